// Round 6
// baseline (413.433 us; speedup 1.0000x reference)
//
#include <hip/hip_runtime.h>

#define NLVL 14
#define NSHARD 16

struct ZeroArgs { unsigned long long zoff[13]; };

__device__ __forceinline__ float fma4(float4 v, float4 w, float acc) {
    acc = fmaf(v.x, w.x, acc);
    acc = fmaf(v.y, w.y, acc);
    acc = fmaf(v.z, w.z, acc);
    return fmaf(v.w, w.w, acc);
}

// exclusive prefix over a 256-thread block, one atomicAdd per block.
__device__ __forceinline__ int block_scan_base(int mycnt, int* gcnt, int& myoff) {
    __shared__ int wsum[4];
    __shared__ int base;
    int lane = threadIdx.x & 63, wid = threadIdx.x >> 6;
    int scan = mycnt;
    #pragma unroll
    for (int d = 1; d < 64; d <<= 1) {
        int tv = __shfl_up(scan, d, 64);
        if (lane >= d) scan += tv;
    }
    if (lane == 63) wsum[wid] = scan;
    __syncthreads();
    if (threadIdx.x == 0) {
        int tot = 0;
        #pragma unroll
        for (int i = 0; i < 4; i++) { int tv = wsum[i]; wsum[i] = tot; tot += tv; }
        base = tot ? atomicAdd(gcnt, tot) : 0;
    }
    __syncthreads();
    myoff = wsum[wid] + scan - mycnt;
    return base;
}

// ---- level-0 mask compaction tile ----
__device__ void compact0_tile(const float4* __restrict__ mask4, int* __restrict__ idxmap,
                              int* __restrict__ coords, int* __restrict__ cnt, int cap, int tile) {
    int t = threadIdx.x;
    int g0 = tile * 1024 + t;
    float4 m[4];
    #pragma unroll
    for (int j = 0; j < 4; j++) m[j] = mask4[g0 + j * 256];
    int pr[16];
    int mycnt = 0;
    #pragma unroll
    for (int j = 0; j < 4; j++) {
        pr[4 * j + 0] = m[j].x > 0.5f;
        pr[4 * j + 1] = m[j].y > 0.5f;
        pr[4 * j + 2] = m[j].z > 0.5f;
        pr[4 * j + 3] = m[j].w > 0.5f;
        mycnt += pr[4 * j] + pr[4 * j + 1] + pr[4 * j + 2] + pr[4 * j + 3];
    }
    int myoff;
    int base = block_scan_base(mycnt, cnt, myoff);
    int slot = base + myoff;
    #pragma unroll
    for (int j = 0; j < 4; j++) {
        int e0 = (g0 + j * 256) << 2;
        int wv[4];
        #pragma unroll
        for (int k = 0; k < 4; k++) {
            wv[k] = -1;
            if (pr[4 * j + k]) {
                int sl = slot++;
                if (sl < cap) { wv[k] = sl; coords[sl] = e0 + k; }
            }
        }
        *(int4*)(idxmap + e0) = make_int4(wv[0], wv[1], wv[2], wv[3]);
    }
}

// ---- downsample + neighbor lists (byte offsets, zero-row remap) ----
__device__ void down_nbr(const int* __restrict__ idx_in, int HinB,
                         int* __restrict__ idx_out, int* __restrict__ nbr_out,
                         int* __restrict__ cnt_out, int HoutB, int cap_out,
                         int zofs, int bb) {
    int Hout = 1 << HoutB, Hin = 1 << HinB;
    int S = Hout * Hout;
    int S4 = (S + 3) >> 2;
    int o4 = bb * 256 + threadIdx.x;
    int e0 = o4 << 2;
    int jv[4][9];
    int pr[4] = {0, 0, 0, 0};
    #pragma unroll
    for (int k = 0; k < 4; k++)
        #pragma unroll
        for (int tap = 0; tap < 9; tap++) jv[k][tap] = -1;
    if (o4 < S4) {
        int r = e0 >> HoutB, c0 = e0 & (Hout - 1);
        int w[3][12];
        #pragma unroll
        for (int a = 0; a < 3; a++) {
            int rr = 2 * r + a - 1;
            bool rok = (unsigned)rr < (unsigned)Hin;
            const int* rowp = idx_in + ((size_t)(rok ? rr : 0) << HinB) + 2 * c0;
            int4 L = (rok && c0 > 0) ? *(const int4*)(rowp - 4) : make_int4(-1, -1, -1, -1);
            int4 M = rok ? *(const int4*)rowp : make_int4(-1, -1, -1, -1);
            int4 R = rok ? *(const int4*)(rowp + 4) : make_int4(-1, -1, -1, -1);
            w[a][0] = L.x; w[a][1] = L.y; w[a][2]  = L.z; w[a][3]  = L.w;
            w[a][4] = M.x; w[a][5] = M.y; w[a][6]  = M.z; w[a][7]  = M.w;
            w[a][8] = R.x; w[a][9] = R.y; w[a][10] = R.z; w[a][11] = R.w;
        }
        #pragma unroll
        for (int k = 0; k < 4; k++) {
            #pragma unroll
            for (int a = 0; a < 3; a++)
                #pragma unroll
                for (int b = 0; b < 3; b++)
                    jv[k][a * 3 + b] = w[a][2 * k + b + 3];
            pr[k] = ((jv[k][4] & jv[k][5] & jv[k][7] & jv[k][8]) >= 0);
        }
    }
    int mycnt = pr[0] + pr[1] + pr[2] + pr[3];
    int myoff;
    int base = block_scan_base(mycnt, cnt_out, myoff);
    int slot = base + myoff;
    int wv[4] = {-1, -1, -1, -1};
    #pragma unroll
    for (int k = 0; k < 4; k++) {
        if (pr[k]) {
            int sl = slot++;
            if (sl < cap_out) {
                wv[k] = sl;
                #pragma unroll
                for (int tap = 0; tap < 9; tap++) {
                    int j = jv[k][tap];
                    nbr_out[sl * 9 + tap] = (j < 0) ? zofs : (j << 7);
                }
            }
        }
    }
    if (o4 < S4)
        *(int4*)(idx_out + e0) = make_int4(wv[0], wv[1], wv[2], wv[3]);
}

// ---- conv 3x3 s2 32->32: unconditional byte-offset gathers, folded pool ----
__device__ void conv_bs(const char* __restrict__ vprevb, const float* __restrict__ wlvl,
                        const int* __restrict__ nbr, int n,
                        float* __restrict__ vals, float* __restrict__ poolp,
                        int b0, int nbk, int shard) {
    __shared__ int s_j[144];
    int t = threadIdx.x;
    int ciq = t & 7, co = t >> 3;
    int ciq16 = ciq << 4;
    float4 wreg[9];
    #pragma unroll
    for (int tap = 0; tap < 9; tap++)
        wreg[tap] = *(const float4*)(wlvl + ((tap * 32 + co) << 5) + (ciq << 2));
    float psum = 0.f;
    int ngr = (n + 15) >> 4;
    for (int grp = b0; grp < ngr; grp += nbk) {
        __syncthreads();
        if (t < 144) {
            int gi = grp * 144 + t;
            s_j[t] = (gi < n * 9) ? nbr[gi] : 0;
        }
        __syncthreads();
        #pragma unroll 2
        for (int g = 0; g < 16; g += 2) {
            int s0 = (grp << 4) + g, s1 = s0 + 1;
            float4 v0[9], v1[9];
            #pragma unroll
            for (int tap = 0; tap < 9; tap++) {
                v0[tap] = *(const float4*)(vprevb + s_j[g * 9 + tap] + ciq16);
                v1[tap] = *(const float4*)(vprevb + s_j[g * 9 + 9 + tap] + ciq16);
            }
            float a0 = 0.f, a1 = 0.f;
            #pragma unroll
            for (int tap = 0; tap < 9; tap++) {
                a0 = fma4(v0[tap], wreg[tap], a0);
                a1 = fma4(v1[tap], wreg[tap], a1);
            }
            a0 += __shfl_xor(a0, 1); a0 += __shfl_xor(a0, 2); a0 += __shfl_xor(a0, 4);
            a1 += __shfl_xor(a1, 1); a1 += __shfl_xor(a1, 2); a1 += __shfl_xor(a1, 4);
            if (ciq == 0) {
                if (s0 < n) { float r0 = fmaxf(a0, 0.f); vals[((size_t)s0 << 5) + co] = r0; psum += r0; }
                if (s1 < n) { float r1 = fmaxf(a1, 0.f); vals[((size_t)s1 << 5) + co] = r1; psum += r1; }
            }
        }
    }
    if (ciq == 0 && psum != 0.f) atomicAdd(&poolp[shard * 448 + co], psum);
}

// ---- conv0 (5x5, cin=1): LDS-staged windows, folded pool ----
__device__ void conv0_bs(const float* __restrict__ x, const float* __restrict__ w1,
                         const int* __restrict__ coords0, int n,
                         float* __restrict__ vals0, float* __restrict__ poolp,
                         int b0, int nbk, int shard) {
    __shared__ float lw[800];
    __shared__ float lx[8][28];
    __shared__ float red[256];
    int t = threadIdx.x;
    for (int i = t; i < 800; i += 256) lw[i] = w1[i];
    int sl = t >> 5, ch = t & 31;
    float psum = 0.f;
    int ngr = (n + 7) >> 3;
    for (int grp = b0; grp < ngr; grp += nbk) {
        __syncthreads();
        if (t < 200) {
            int slot = t / 25, tap = t - slot * 25;
            int s = (grp << 3) + slot;
            float v = 0.f;
            if (s < n) {
                int p = coords0[s];
                int r = p >> 11, c = p & 2047;
                int a = tap / 5, b = tap - a * 5;
                int rr = r + a - 2, cc = c + b - 2;
                if ((unsigned)rr < 2048u && (unsigned)cc < 2048u)
                    v = x[(rr << 11) + cc];
            }
            lx[slot][tap] = v;
        }
        __syncthreads();
        int s = (grp << 3) + sl;
        float acc = 0.f;
        #pragma unroll
        for (int tap = 0; tap < 25; tap++)
            acc = fmaf(lx[sl][tap], lw[tap * 32 + ch], acc);
        if (s < n) {
            float r0 = fmaxf(acc, 0.f);
            vals0[((size_t)s << 5) + ch] = r0;
            psum += r0;
        }
    }
    __syncthreads();
    red[t] = psum;
    __syncthreads();
    if (t < 32) {
        float tot = 0.f;
        #pragma unroll
        for (int q = 0; q < 8; q++) tot += red[t + 32 * q];
        if (tot != 0.f) atomicAdd(&poolp[shard * 448 + t], tot);
    }
}

// F0 = compaction (0..1023) + weight transpose (1024..1491) + zero-rows (1492)
__global__ __launch_bounds__(256) void k_f0(
    const float4* __restrict__ mask4, int* __restrict__ idxmap,
    int* __restrict__ coords, int* __restrict__ cnt, int cap,
    const float* __restrict__ w, float* __restrict__ wt,
    char* __restrict__ wsbase, ZeroArgs za) {
    if (blockIdx.x == 1492) {
        for (int i = threadIdx.x; i < 13 * 32; i += 256)
            *(float*)(wsbase + za.zoff[i >> 5] + ((i & 31) << 2)) = 0.f;
        return;
    }
    if (blockIdx.x >= 1024) {
        int t = (int)(blockIdx.x - 1024) * 256 + threadIdx.x;
        if (t < 13 * 9 * 32 * 32) {
            int ci = t & 31, co = (t >> 5) & 31, tp = t >> 10;
            wt[(tp << 10) + (co << 5) + ci] = w[(tp << 10) + (ci << 5) + co];
        }
        return;
    }
    compact0_tile(mask4, idxmap, coords, cnt, cap, blockIdx.x);
}

// F1 = down1+nbr1 (0..1023) + conv0 (1024..3071) + wm warm (3072..3095)
__global__ __launch_bounds__(256) void k_f1(
    const int* __restrict__ idx0, int* __restrict__ idx1, int* __restrict__ nbr1,
    int* __restrict__ cnt1, int cap1, int zofs1,
    const float* __restrict__ x, const float* __restrict__ w1,
    const int* __restrict__ coords0, const int* __restrict__ cnt0, int cap0,
    float* __restrict__ vals0, float* __restrict__ poolp,
    const float* __restrict__ wm1, const float* __restrict__ wm2, float* __restrict__ dummy) {
    if (blockIdx.x < 1024) {
        down_nbr(idx0, 11, idx1, nbr1, cnt1, 10, cap1, zofs1, blockIdx.x);
        return;
    }
    if (blockIdx.x >= 3072) {
        int t = (int)(blockIdx.x - 3072) * 256 + threadIdx.x;
        const float4* a = (const float4*)wm1;
        const float4* b = (const float4*)wm2;
        float acc = 0.f;
        for (int i = t; i < 28672; i += 6144) { float4 v = a[i]; acc += v.x + v.y + v.z + v.w; }
        for (int i = t; i < 8192; i += 6144)  { float4 v = b[i]; acc += v.x + v.y + v.z + v.w; }
        if (acc == 1234.56789f) dummy[0] = acc;
        return;
    }
    int n = *cnt0; if (n > cap0) n = cap0;
    conv0_bs(x, w1, coords0, n, vals0, poolp, blockIdx.x - 1024, 2048, blockIdx.x & (NSHARD - 1));
}

// F_i (i=2..7): down_i (+nbr_i) fused with conv_{i-1} (+pool_{i-1})
__global__ __launch_bounds__(256) void k_flevel(
    int downB,
    const int* __restrict__ idx_in, int HinB,
    int* __restrict__ idx_out, int* __restrict__ nbr_out, int* __restrict__ cnt_out,
    int HoutB, int cap_out, int zofs,
    const char* __restrict__ vprevb, const float* __restrict__ wlvl,
    const int* __restrict__ nbr_c, const int* __restrict__ cnt_c, int cap_c,
    float* __restrict__ vals_c, float* __restrict__ poolp) {
    if ((int)blockIdx.x < downB) {
        down_nbr(idx_in, HinB, idx_out, nbr_out, cnt_out, HoutB, cap_out, zofs, blockIdx.x);
        return;
    }
    int n = *cnt_c; if (n > cap_c) n = cap_c;
    conv_bs(vprevb, wlvl, nbr_c, n, vals_c, poolp,
            blockIdx.x - downB, gridDim.x - downB, blockIdx.x & (NSHARD - 1));
}

// TAIL: conv7..conv13 + down8..down11 + pools 7..13 + feat + MLP, one block.
__global__ __launch_bounds__(1024) void k_tail(
    const int* __restrict__ cnt, const float* __restrict__ poolsh,
    const char* __restrict__ vals6b, const int* __restrict__ nbr7,
    const int* __restrict__ idx7, const float* __restrict__ wt,
    const float* __restrict__ wm1, const float* __restrict__ bm1,
    const float* __restrict__ wm2, const float* __restrict__ bm2,
    float* __restrict__ out) {
    __shared__ __align__(16) float v7[256 * 32];
    __shared__ __align__(16) float v8[64 * 32];
    __shared__ __align__(16) float v9[16 * 32];
    __shared__ __align__(16) float v10[4 * 32];
    __shared__ float v11[32], v12[32], v13[32];
    __shared__ int snbr7[2304];
    __shared__ int nbr8s[64 * 9], idx8s[64];
    __shared__ int nbr9s[16 * 9], idx9s[16];
    __shared__ int nbr10s[4 * 9], idx10s[4];
    __shared__ int s_n[4];
    __shared__ float pol[4][32];
    __shared__ float red[256];
    __shared__ float feat[448], h[256], part[1024];

    int t = threadIdx.x;
    int ciq = t & 7, co = (t >> 3) & 31, sl = t >> 8;
    int ciq16 = ciq << 4;

    if (t == 0) { int n = cnt[7]; s_n[0] = n > 256 ? 256 : n; }
    __syncthreads();
    int n7 = s_n[0];
    for (int i = t; i < n7 * 9; i += 1024) snbr7[i] = nbr7[i];
    __syncthreads();
    {   // conv7: gather vals6 (global, byte offsets incl zero-row)
        const float* wl = wt + (size_t)6 * 9216;
        float4 wreg[9];
        #pragma unroll
        for (int tap = 0; tap < 9; tap++)
            wreg[tap] = *(const float4*)(wl + ((tap * 32 + co) << 5) + (ciq << 2));
        for (int s = sl; s < n7; s += 4) {
            float a0 = 0.f;
            #pragma unroll
            for (int tap = 0; tap < 9; tap++)
                a0 = fma4(*(const float4*)(vals6b + snbr7[s * 9 + tap] + ciq16), wreg[tap], a0);
            a0 += __shfl_xor(a0, 1); a0 += __shfl_xor(a0, 2); a0 += __shfl_xor(a0, 4);
            if (ciq == 0) v7[s * 32 + co] = fmaxf(a0, 0.f);
        }
    }
    __syncthreads();
    if (t < 256) {   // pool7 partials
        int g = t >> 5, ch = t & 31;
        float s = 0.f;
        for (int q = g; q < n7; q += 8) s += v7[q * 32 + ch];
        red[t] = s;
    }
    __syncthreads();
    if (t < 32) { float tot = 0.f; for (int g = 0; g < 8; g++) tot += red[t + 32 * g]; pol[0][t] = tot; }
    if (t < 64) {   // down8 from idx7 (16x16 global), wave-0 deterministic scan
        int r = t >> 3, c = t & 7;
        int jv[9];
        #pragma unroll
        for (int tap = 0; tap < 9; tap++) {
            int a = tap / 3, b = tap - a * 3;
            int rr = 2 * r + a - 1, cc = 2 * c + b - 1;
            jv[tap] = ((unsigned)rr < 16u && (unsigned)cc < 16u) ? idx7[rr * 16 + cc] : -1;
        }
        int pred = ((jv[4] & jv[5] & jv[7] & jv[8]) >= 0);
        unsigned long long b = __ballot(pred);
        int slot = (int)__popcll(b & ((1ull << t) - 1ull));
        idx8s[t] = pred ? slot : -1;
        if (pred)
            #pragma unroll
            for (int tap = 0; tap < 9; tap++) nbr8s[slot * 9 + tap] = jv[tap];
        if (t == 0) s_n[1] = (int)__popcll(b);
    }
    __syncthreads();
    int n8 = s_n[1];
    {   // conv8 from v7 (LDS)
        const float* wl = wt + (size_t)7 * 9216;
        float4 wreg[9];
        #pragma unroll
        for (int tap = 0; tap < 9; tap++)
            wreg[tap] = *(const float4*)(wl + ((tap * 32 + co) << 5) + (ciq << 2));
        for (int s = sl; s < n8; s += 4) {
            float a0 = 0.f;
            #pragma unroll
            for (int tap = 0; tap < 9; tap++) {
                int j = nbr8s[s * 9 + tap];
                if (j >= 0) a0 = fma4(*(const float4*)&v7[j * 32 + (ciq << 2)], wreg[tap], a0);
            }
            a0 += __shfl_xor(a0, 1); a0 += __shfl_xor(a0, 2); a0 += __shfl_xor(a0, 4);
            if (ciq == 0) v8[s * 32 + co] = fmaxf(a0, 0.f);
        }
    }
    __syncthreads();
    if (t < 256) {
        int g = t >> 5, ch = t & 31;
        float s = 0.f;
        for (int q = g; q < n8; q += 8) s += v8[q * 32 + ch];
        red[t] = s;
    }
    __syncthreads();
    if (t < 32) { float tot = 0.f; for (int g = 0; g < 8; g++) tot += red[t + 32 * g]; pol[1][t] = tot; }
    if (t < 16) {   // down9 from idx8s (8x8)
        int r = t >> 2, c = t & 3;
        int jv[9];
        #pragma unroll
        for (int tap = 0; tap < 9; tap++) {
            int a = tap / 3, b = tap - a * 3;
            int rr = 2 * r + a - 1, cc = 2 * c + b - 1;
            jv[tap] = ((unsigned)rr < 8u && (unsigned)cc < 8u) ? idx8s[rr * 8 + cc] : -1;
        }
        int pred = ((jv[4] & jv[5] & jv[7] & jv[8]) >= 0);
        unsigned long long b = __ballot(pred);
        int slot = (int)__popcll(b & ((1ull << t) - 1ull));
        idx9s[t] = pred ? slot : -1;
        if (pred)
            #pragma unroll
            for (int tap = 0; tap < 9; tap++) nbr9s[slot * 9 + tap] = jv[tap];
        if (t == 0) s_n[2] = (int)__popcll(b);
    }
    __syncthreads();
    int n9 = s_n[2];
    {   // conv9 from v8
        const float* wl = wt + (size_t)8 * 9216;
        float4 wreg[9];
        #pragma unroll
        for (int tap = 0; tap < 9; tap++)
            wreg[tap] = *(const float4*)(wl + ((tap * 32 + co) << 5) + (ciq << 2));
        for (int s = sl; s < n9; s += 4) {
            float a0 = 0.f;
            #pragma unroll
            for (int tap = 0; tap < 9; tap++) {
                int j = nbr9s[s * 9 + tap];
                if (j >= 0) a0 = fma4(*(const float4*)&v8[j * 32 + (ciq << 2)], wreg[tap], a0);
            }
            a0 += __shfl_xor(a0, 1); a0 += __shfl_xor(a0, 2); a0 += __shfl_xor(a0, 4);
            if (ciq == 0) v9[s * 32 + co] = fmaxf(a0, 0.f);
        }
    }
    __syncthreads();
    if (t < 32) { float s = 0.f; for (int q = 0; q < n9; q++) s += v9[q * 32 + t]; pol[2][t] = s; }
    if (t < 4) {    // down10 from idx9s (4x4)
        int r = t >> 1, c = t & 1;
        int jv[9];
        #pragma unroll
        for (int tap = 0; tap < 9; tap++) {
            int a = tap / 3, b = tap - a * 3;
            int rr = 2 * r + a - 1, cc = 2 * c + b - 1;
            jv[tap] = ((unsigned)rr < 4u && (unsigned)cc < 4u) ? idx9s[rr * 4 + cc] : -1;
        }
        int pred = ((jv[4] & jv[5] & jv[7] & jv[8]) >= 0);
        unsigned long long b = __ballot(pred);
        int slot = (int)__popcll(b & ((1ull << t) - 1ull));
        idx10s[t] = pred ? slot : -1;
        if (pred)
            #pragma unroll
            for (int tap = 0; tap < 9; tap++) nbr10s[slot * 9 + tap] = jv[tap];
        if (t == 0) s_n[3] = (int)__popcll(b);
    }
    __syncthreads();
    int n10 = s_n[3];
    {   // conv10 from v9
        const float* wl = wt + (size_t)9 * 9216;
        float4 wreg[9];
        #pragma unroll
        for (int tap = 0; tap < 9; tap++)
            wreg[tap] = *(const float4*)(wl + ((tap * 32 + co) << 5) + (ciq << 2));
        for (int s = sl; s < n10; s += 4) {
            float a0 = 0.f;
            #pragma unroll
            for (int tap = 0; tap < 9; tap++) {
                int j = nbr10s[s * 9 + tap];
                if (j >= 0) a0 = fma4(*(const float4*)&v9[j * 32 + (ciq << 2)], wreg[tap], a0);
            }
            a0 += __shfl_xor(a0, 1); a0 += __shfl_xor(a0, 2); a0 += __shfl_xor(a0, 4);
            if (ciq == 0) v10[s * 32 + co] = fmaxf(a0, 0.f);
        }
    }
    __syncthreads();
    if (t < 32) { float s = 0.f; for (int q = 0; q < n10; q++) s += v10[q * 32 + t]; pol[3][t] = s; }
    // down11: level-10 grid is 2x2 -> level-11 single cell
    int nbr11[9];
    #pragma unroll
    for (int tap = 0; tap < 9; tap++) {
        int a = tap / 3, b = tap - a * 3;
        int rr = a - 1, cc = b - 1;
        nbr11[tap] = ((unsigned)rr < 2u && (unsigned)cc < 2u) ? idx10s[rr * 2 + cc] : -1;
    }
    int n11 = ((nbr11[4] & nbr11[5] & nbr11[7] & nbr11[8]) >= 0) ? 1 : 0;
    if (sl == 0) {   // conv11 from v10
        const float* wl = wt + (size_t)10 * 9216;
        float a0 = 0.f;
        #pragma unroll
        for (int tap = 0; tap < 9; tap++) {
            int j = nbr11[tap];
            if (j >= 0) {
                float4 wv = *(const float4*)(wl + ((tap * 32 + co) << 5) + (ciq << 2));
                a0 = fma4(*(const float4*)&v10[j * 32 + (ciq << 2)], wv, a0);
            }
        }
        a0 += __shfl_xor(a0, 1); a0 += __shfl_xor(a0, 2); a0 += __shfl_xor(a0, 4);
        if (ciq == 0) v11[co] = n11 ? fmaxf(a0, 0.f) : 0.f;
    }
    __syncthreads();
    if (sl == 0) {   // conv12: center tap only
        const float* wl = wt + (size_t)11 * 9216;
        float4 wv = *(const float4*)(wl + ((4 * 32 + co) << 5) + (ciq << 2));
        float a0 = n11 ? fma4(*(const float4*)&v11[ciq << 2], wv, 0.f) : 0.f;
        a0 += __shfl_xor(a0, 1); a0 += __shfl_xor(a0, 2); a0 += __shfl_xor(a0, 4);
        if (ciq == 0) v12[co] = n11 ? fmaxf(a0, 0.f) : 0.f;
    }
    __syncthreads();
    if (sl == 0) {   // conv13
        const float* wl = wt + (size_t)12 * 9216;
        float4 wv = *(const float4*)(wl + ((4 * 32 + co) << 5) + (ciq << 2));
        float a0 = n11 ? fma4(*(const float4*)&v12[ciq << 2], wv, 0.f) : 0.f;
        a0 += __shfl_xor(a0, 1); a0 += __shfl_xor(a0, 2); a0 += __shfl_xor(a0, 4);
        if (ciq == 0) v13[co] = n11 ? fmaxf(a0, 0.f) : 0.f;
    }
    __syncthreads();
    // feat assembly
    if (t < 224) {
        float s = 0.f;
        #pragma unroll
        for (int sh = 0; sh < NSHARD; sh++) s += poolsh[sh * 448 + t];
        float c = (float)cnt[t >> 5]; if (c < 1.f) c = 1.f;
        feat[t] = s / c;
    } else if (t < 448) {
        int l = t >> 5, ch = t & 31;
        float num, den = 1.f;
        if (l <= 10) {
            num = pol[l - 7][ch];
            int nn = s_n[l - 7]; den = (nn > 0) ? (float)nn : 1.f;
        } else {
            num = (l == 11) ? v11[ch] : (l == 12) ? v12[ch] : v13[ch];
            if (!n11) num = 0.f;
        }
        feat[t] = num / den;
    }
    __syncthreads();
    {   // MLP stage 1: 448 -> 256
        int j = t & 255, chunk = t >> 8;
        float acc = (chunk == 0) ? bm1[j] : 0.f;
        int k0 = chunk * 112;
        #pragma unroll 8
        for (int k = k0; k < k0 + 112; k++) acc = fmaf(feat[k], wm1[k * 256 + j], acc);
        part[t] = acc;
    }
    __syncthreads();
    if (t < 256)
        h[t] = fmaxf(part[t] + part[t + 256] + part[t + 512] + part[t + 768], 0.f);
    __syncthreads();
    {   // MLP stage 2: 256 -> 128
        int j2 = t & 127, c2 = t >> 7;
        float a2 = (c2 == 0) ? bm2[j2] : 0.f;
        int kk0 = c2 * 32;
        #pragma unroll 8
        for (int k = kk0; k < kk0 + 32; k++) a2 = fmaf(h[k], wm2[k * 128 + j2], a2);
        part[t] = a2;
    }
    __syncthreads();
    if (t < 128) {
        float sum = 0.f;
        #pragma unroll
        for (int c = 0; c < 8; c++) sum += part[t + 128 * c];
        out[t] = sum;
    }
}

extern "C" void kernel_launch(void* const* d_in, const int* in_sizes, int n_in,
                              void* d_out, int out_size, void* d_ws, size_t ws_size,
                              hipStream_t stream) {
    const float* x    = (const float*)d_in[0];
    const float* mask = (const float*)d_in[1];
    const float* w1   = (const float*)d_in[2];
    const float* wsrc = (const float*)d_in[3];
    const float* wm1  = (const float*)d_in[4];
    const float* bm1  = (const float*)d_in[5];
    const float* wm2  = (const float*)d_in[6];
    const float* bm2  = (const float*)d_in[7];
    float* out = (float*)d_out;
    char* ws = (char*)d_ws;

    static const int Hb[NLVL]   = {11, 10, 9, 8, 7, 6, 5, 4, 3, 2, 1, 0, 0, 0};
    static const int caps[NLVL] = {45056, 43008, 43008, 34816, 16384, 4096,
                                   1024, 256, 64, 16, 4, 1, 1, 1};

    // ws layout: cnt[16]@0, dummy@128, pool shards@256 (16*448 f32), wt@32768
    size_t pool_off = 256;
    size_t wt_off = 32768;
    size_t off = wt_off + (size_t)13 * 9 * 1024 * 4;
    off = (off + 255) & ~(size_t)255;
    size_t coord0_off = off; off += (size_t)caps[0] * 4; off = (off + 255) & ~(size_t)255;
    size_t idx_off[NLVL], nbr_off[NLVL], val_off[NLVL];
    for (int l = 0; l < NLVL; l++) {
        size_t S = (size_t)(1 << Hb[l]) * (1 << Hb[l]);
        size_t sb = S * 4; if (sb < 16) sb = 16;
        idx_off[l] = off; off += sb; off = (off + 255) & ~(size_t)255;
        if (l >= 1) { nbr_off[l] = off; off += (size_t)caps[l] * 36; off = (off + 255) & ~(size_t)255; }
        else nbr_off[l] = 0;
        val_off[l] = off; off += (size_t)(caps[l] + 1) * 128; off = (off + 255) & ~(size_t)255;
    }

    int* cnt = (int*)ws;
    float* poolsh = (float*)(ws + pool_off);
    float* dummy = (float*)(ws + 128);
    float* wt = (float*)(ws + wt_off);

    ZeroArgs za;
    for (int l = 0; l < 13; l++) za.zoff[l] = val_off[l] + (size_t)caps[l] * 128;

    hipMemsetAsync(ws, 0, 32768, stream);   // cnt + pool shards

    k_f0<<<1493, 256, 0, stream>>>(
        (const float4*)mask, (int*)(ws + idx_off[0]), (int*)(ws + coord0_off),
        cnt, caps[0], wsrc, wt, ws, za);

    k_f1<<<3096, 256, 0, stream>>>(
        (const int*)(ws + idx_off[0]), (int*)(ws + idx_off[1]), (int*)(ws + nbr_off[1]),
        cnt + 1, caps[1], caps[0] * 128,
        x, w1, (const int*)(ws + coord0_off), cnt, caps[0],
        (float*)(ws + val_off[0]), poolsh, wm1, wm2, dummy);

    for (int i = 2; i <= 7; i++) {
        int lc = i - 1;
        int Hout = 1 << Hb[i];
        int S4 = (Hout * Hout + 3) >> 2;
        int downB = (S4 + 255) >> 8; if (downB < 1) downB = 1;
        int convB = (caps[lc] + 15) >> 4;
        k_flevel<<<downB + convB, 256, 0, stream>>>(
            downB,
            (const int*)(ws + idx_off[i - 1]), Hb[i - 1],
            (int*)(ws + idx_off[i]), (int*)(ws + nbr_off[i]), cnt + i, Hb[i], caps[i],
            caps[i - 1] * 128,
            (const char*)(ws + val_off[lc - 1]), wt + (size_t)(lc - 1) * 9216,
            (const int*)(ws + nbr_off[lc]), cnt + lc, caps[lc],
            (float*)(ws + val_off[lc]), poolsh + lc * 32);
    }

    k_tail<<<1, 1024, 0, stream>>>(
        cnt, poolsh,
        (const char*)(ws + val_off[6]), (const int*)(ws + nbr_off[7]),
        (const int*)(ws + idx_off[7]), wt,
        wm1, bm1, wm2, bm2, out);
}

// Round 7
// 351.260 us; speedup vs baseline: 1.1770x; 1.1770x over previous
//
#include <hip/hip_runtime.h>

#define NLVL 14
#define NSHARD 16

struct ZeroArgs { unsigned long long zoff[13]; };

__device__ __forceinline__ float fma4(float4 v, float4 w, float acc) {
    acc = fmaf(v.x, w.x, acc);
    acc = fmaf(v.y, w.y, acc);
    acc = fmaf(v.z, w.z, acc);
    return fmaf(v.w, w.w, acc);
}

// exclusive prefix over a 256-thread block, one atomicAdd per block.
__device__ __forceinline__ int block_scan_base(int mycnt, int* gcnt, int& myoff) {
    __shared__ int wsum[4];
    __shared__ int base;
    int lane = threadIdx.x & 63, wid = threadIdx.x >> 6;
    int scan = mycnt;
    #pragma unroll
    for (int d = 1; d < 64; d <<= 1) {
        int tv = __shfl_up(scan, d, 64);
        if (lane >= d) scan += tv;
    }
    if (lane == 63) wsum[wid] = scan;
    __syncthreads();
    if (threadIdx.x == 0) {
        int tot = 0;
        #pragma unroll
        for (int i = 0; i < 4; i++) { int tv = wsum[i]; wsum[i] = tot; tot += tv; }
        base = tot ? atomicAdd(gcnt, tot) : 0;
    }
    __syncthreads();
    myoff = wsum[wid] + scan - mycnt;
    return base;
}

// ---- level-0 mask compaction tile ----
__device__ void compact0_tile(const float4* __restrict__ mask4, int* __restrict__ idxmap,
                              int* __restrict__ coords, int* __restrict__ cnt, int cap, int tile) {
    int t = threadIdx.x;
    int g0 = tile * 1024 + t;
    float4 m[4];
    #pragma unroll
    for (int j = 0; j < 4; j++) m[j] = mask4[g0 + j * 256];
    int pr[16];
    int mycnt = 0;
    #pragma unroll
    for (int j = 0; j < 4; j++) {
        pr[4 * j + 0] = m[j].x > 0.5f;
        pr[4 * j + 1] = m[j].y > 0.5f;
        pr[4 * j + 2] = m[j].z > 0.5f;
        pr[4 * j + 3] = m[j].w > 0.5f;
        mycnt += pr[4 * j] + pr[4 * j + 1] + pr[4 * j + 2] + pr[4 * j + 3];
    }
    int myoff;
    int base = block_scan_base(mycnt, cnt, myoff);
    int slot = base + myoff;
    #pragma unroll
    for (int j = 0; j < 4; j++) {
        int e0 = (g0 + j * 256) << 2;
        int wv[4];
        #pragma unroll
        for (int k = 0; k < 4; k++) {
            wv[k] = -1;
            if (pr[4 * j + k]) {
                int sl = slot++;
                if (sl < cap) { wv[k] = sl; coords[sl] = e0 + k; }
            }
        }
        *(int4*)(idxmap + e0) = make_int4(wv[0], wv[1], wv[2], wv[3]);
    }
}

// ---- downsample + neighbor lists (byte offsets into vals_{l-1}, zero-row remap) ----
__device__ void down_nbr(const int* __restrict__ idx_in, int HinB,
                         int* __restrict__ idx_out, int* __restrict__ nbr_out,
                         int* __restrict__ cnt_out, int HoutB, int cap_out,
                         int zofs, int bb) {
    int Hout = 1 << HoutB, Hin = 1 << HinB;
    int S = Hout * Hout;
    int S4 = (S + 3) >> 2;
    int o4 = bb * 256 + threadIdx.x;
    int e0 = o4 << 2;
    int jv[4][9];
    int pr[4] = {0, 0, 0, 0};
    #pragma unroll
    for (int k = 0; k < 4; k++)
        #pragma unroll
        for (int tap = 0; tap < 9; tap++) jv[k][tap] = -1;
    if (o4 < S4) {
        if (HoutB >= 2) {
            int r = e0 >> HoutB, c0 = e0 & (Hout - 1);
            int w[3][12];
            #pragma unroll
            for (int a = 0; a < 3; a++) {
                int rr = 2 * r + a - 1;
                bool rok = (unsigned)rr < (unsigned)Hin;
                const int* rowp = idx_in + ((size_t)(rok ? rr : 0) << HinB) + 2 * c0;
                int4 L = (rok && c0 > 0) ? *(const int4*)(rowp - 4) : make_int4(-1, -1, -1, -1);
                int4 M = rok ? *(const int4*)rowp : make_int4(-1, -1, -1, -1);
                int4 R = rok ? *(const int4*)(rowp + 4) : make_int4(-1, -1, -1, -1);
                w[a][0] = L.x; w[a][1] = L.y; w[a][2]  = L.z; w[a][3]  = L.w;
                w[a][4] = M.x; w[a][5] = M.y; w[a][6]  = M.z; w[a][7]  = M.w;
                w[a][8] = R.x; w[a][9] = R.y; w[a][10] = R.z; w[a][11] = R.w;
            }
            #pragma unroll
            for (int k = 0; k < 4; k++) {
                #pragma unroll
                for (int a = 0; a < 3; a++)
                    #pragma unroll
                    for (int b = 0; b < 3; b++)
                        jv[k][a * 3 + b] = w[a][2 * k + b + 3];
                pr[k] = ((jv[k][4] & jv[k][5] & jv[k][7] & jv[k][8]) >= 0);
            }
        } else {   // Hout 1 or 2 (scalar path)
            #pragma unroll
            for (int k = 0; k < 4; k++) {
                int p = e0 + k;
                if (p < S) {
                    int r = p >> HoutB, c = p & (Hout - 1);
                    #pragma unroll
                    for (int a = 0; a < 3; a++)
                        #pragma unroll
                        for (int b = 0; b < 3; b++) {
                            int rr = 2 * r + a - 1, cc = 2 * c + b - 1;
                            if ((unsigned)rr < (unsigned)Hin && (unsigned)cc < (unsigned)Hin)
                                jv[k][a * 3 + b] = idx_in[((size_t)rr << HinB) + cc];
                        }
                    pr[k] = ((jv[k][4] & jv[k][5] & jv[k][7] & jv[k][8]) >= 0);
                }
            }
        }
    }
    int mycnt = pr[0] + pr[1] + pr[2] + pr[3];
    int myoff;
    int base = block_scan_base(mycnt, cnt_out, myoff);
    int slot = base + myoff;
    int wv[4] = {-1, -1, -1, -1};
    #pragma unroll
    for (int k = 0; k < 4; k++) {
        if (pr[k]) {
            int sl = slot++;
            if (sl < cap_out) {
                wv[k] = sl;
                #pragma unroll
                for (int tap = 0; tap < 9; tap++) {
                    int j = jv[k][tap];
                    nbr_out[sl * 9 + tap] = (j < 0) ? zofs : (j << 7);
                }
            }
        }
    }
    if (o4 < S4) {
        if (S >= 4) *(int4*)(idx_out + e0) = make_int4(wv[0], wv[1], wv[2], wv[3]);
        else {
            #pragma unroll
            for (int k = 0; k < 4; k++) if (e0 + k < S) idx_out[e0 + k] = wv[k];
        }
    }
}

// ---- conv 3x3 s2 32->32: unconditional byte-offset gathers, folded pool ----
__device__ void conv_bs(const char* __restrict__ vprevb, const float* __restrict__ wlvl,
                        const int* __restrict__ nbr, int n,
                        float* __restrict__ vals, float* __restrict__ poolp,
                        int b0, int nbk, int shard) {
    __shared__ int s_j[144];
    int t = threadIdx.x;
    int ciq = t & 7, co = t >> 3;
    int ciq16 = ciq << 4;
    float4 wreg[9];
    #pragma unroll
    for (int tap = 0; tap < 9; tap++)
        wreg[tap] = *(const float4*)(wlvl + ((tap * 32 + co) << 5) + (ciq << 2));
    float psum = 0.f;
    int ngr = (n + 15) >> 4;
    for (int grp = b0; grp < ngr; grp += nbk) {
        __syncthreads();
        if (t < 144) {
            int gi = grp * 144 + t;
            s_j[t] = (gi < n * 9) ? nbr[gi] : 0;
        }
        __syncthreads();
        #pragma unroll 2
        for (int g = 0; g < 16; g += 2) {
            int s0 = (grp << 4) + g, s1 = s0 + 1;
            float4 v0[9], v1[9];
            #pragma unroll
            for (int tap = 0; tap < 9; tap++) {
                v0[tap] = *(const float4*)(vprevb + s_j[g * 9 + tap] + ciq16);
                v1[tap] = *(const float4*)(vprevb + s_j[g * 9 + 9 + tap] + ciq16);
            }
            float a0 = 0.f, a1 = 0.f;
            #pragma unroll
            for (int tap = 0; tap < 9; tap++) {
                a0 = fma4(v0[tap], wreg[tap], a0);
                a1 = fma4(v1[tap], wreg[tap], a1);
            }
            a0 += __shfl_xor(a0, 1); a0 += __shfl_xor(a0, 2); a0 += __shfl_xor(a0, 4);
            a1 += __shfl_xor(a1, 1); a1 += __shfl_xor(a1, 2); a1 += __shfl_xor(a1, 4);
            if (ciq == 0) {
                if (s0 < n) { float r0 = fmaxf(a0, 0.f); vals[((size_t)s0 << 5) + co] = r0; psum += r0; }
                if (s1 < n) { float r1 = fmaxf(a1, 0.f); vals[((size_t)s1 << 5) + co] = r1; psum += r1; }
            }
        }
    }
    if (ciq == 0 && psum != 0.f) atomicAdd(&poolp[shard * 448 + co], psum);
}

// ---- conv0 (5x5, cin=1): LDS-staged windows, folded pool ----
__device__ void conv0_bs(const float* __restrict__ x, const float* __restrict__ w1,
                         const int* __restrict__ coords0, int n,
                         float* __restrict__ vals0, float* __restrict__ poolp,
                         int b0, int nbk, int shard) {
    __shared__ float lw[800];
    __shared__ float lx[8][28];
    __shared__ float red[256];
    int t = threadIdx.x;
    for (int i = t; i < 800; i += 256) lw[i] = w1[i];
    int sl = t >> 5, ch = t & 31;
    float psum = 0.f;
    int ngr = (n + 7) >> 3;
    for (int grp = b0; grp < ngr; grp += nbk) {
        __syncthreads();
        if (t < 200) {
            int slot = t / 25, tap = t - slot * 25;
            int s = (grp << 3) + slot;
            float v = 0.f;
            if (s < n) {
                int p = coords0[s];
                int r = p >> 11, c = p & 2047;
                int a = tap / 5, b = tap - a * 5;
                int rr = r + a - 2, cc = c + b - 2;
                if ((unsigned)rr < 2048u && (unsigned)cc < 2048u)
                    v = x[(rr << 11) + cc];
            }
            lx[slot][tap] = v;
        }
        __syncthreads();
        int s = (grp << 3) + sl;
        float acc = 0.f;
        #pragma unroll
        for (int tap = 0; tap < 25; tap++)
            acc = fmaf(lx[sl][tap], lw[tap * 32 + ch], acc);
        if (s < n) {
            float r0 = fmaxf(acc, 0.f);
            vals0[((size_t)s << 5) + ch] = r0;
            psum += r0;
        }
    }
    __syncthreads();
    red[t] = psum;
    __syncthreads();
    if (t < 32) {
        float tot = 0.f;
        #pragma unroll
        for (int q = 0; q < 8; q++) tot += red[t + 32 * q];
        if (tot != 0.f) atomicAdd(&poolp[shard * 448 + t], tot);
    }
}

// F0 = compaction (0..1023) + weight transpose (1024..1491) + zero-rows (1492)
__global__ __launch_bounds__(256) void k_f0(
    const float4* __restrict__ mask4, int* __restrict__ idxmap,
    int* __restrict__ coords, int* __restrict__ cnt, int cap,
    const float* __restrict__ w, float* __restrict__ wt,
    char* __restrict__ wsbase, ZeroArgs za) {
    if (blockIdx.x == 1492) {
        for (int i = threadIdx.x; i < 13 * 32; i += 256)
            *(float*)(wsbase + za.zoff[i >> 5] + ((i & 31) << 2)) = 0.f;
        return;
    }
    if (blockIdx.x >= 1024) {
        int t = (int)(blockIdx.x - 1024) * 256 + threadIdx.x;
        if (t < 13 * 9 * 32 * 32) {
            int ci = t & 31, co = (t >> 5) & 31, tp = t >> 10;
            wt[(tp << 10) + (co << 5) + ci] = w[(tp << 10) + (ci << 5) + co];
        }
        return;
    }
    compact0_tile(mask4, idxmap, coords, cnt, cap, blockIdx.x);
}

// F1 = down1+nbr1 (0..1023) + conv0 (1024..3071) + wm warm (3072..3095)
__global__ __launch_bounds__(256) void k_f1(
    const int* __restrict__ idx0, int* __restrict__ idx1, int* __restrict__ nbr1,
    int* __restrict__ cnt1, int cap1, int zofs1,
    const float* __restrict__ x, const float* __restrict__ w1,
    const int* __restrict__ coords0, const int* __restrict__ cnt0, int cap0,
    float* __restrict__ vals0, float* __restrict__ poolp,
    const float* __restrict__ wm1, const float* __restrict__ wm2, float* __restrict__ dummy) {
    if (blockIdx.x < 1024) {
        down_nbr(idx0, 11, idx1, nbr1, cnt1, 10, cap1, zofs1, blockIdx.x);
        return;
    }
    if (blockIdx.x >= 3072) {
        int t = (int)(blockIdx.x - 3072) * 256 + threadIdx.x;
        const float4* a = (const float4*)wm1;
        const float4* b = (const float4*)wm2;
        float acc = 0.f;
        for (int i = t; i < 28672; i += 6144) { float4 v = a[i]; acc += v.x + v.y + v.z + v.w; }
        for (int i = t; i < 8192; i += 6144)  { float4 v = b[i]; acc += v.x + v.y + v.z + v.w; }
        if (acc == 1234.56789f) dummy[0] = acc;
        return;
    }
    int n = *cnt0; if (n > cap0) n = cap0;
    conv0_bs(x, w1, coords0, n, vals0, poolp, blockIdx.x - 1024, 2048, blockIdx.x & (NSHARD - 1));
}

// F_i (i=2..10): down_i (+nbr_i) fused with conv_{i-1} (+pool_{i-1})
__global__ __launch_bounds__(256) void k_flevel(
    int downB,
    const int* __restrict__ idx_in, int HinB,
    int* __restrict__ idx_out, int* __restrict__ nbr_out, int* __restrict__ cnt_out,
    int HoutB, int cap_out, int zofs,
    const char* __restrict__ vprevb, const float* __restrict__ wlvl,
    const int* __restrict__ nbr_c, const int* __restrict__ cnt_c, int cap_c,
    float* __restrict__ vals_c, float* __restrict__ poolp) {
    if ((int)blockIdx.x < downB) {
        down_nbr(idx_in, HinB, idx_out, nbr_out, cnt_out, HoutB, cap_out, zofs, blockIdx.x);
        return;
    }
    int n = *cnt_c; if (n > cap_c) n = cap_c;
    conv_bs(vprevb, wlvl, nbr_c, n, vals_c, poolp,
            blockIdx.x - downB, gridDim.x - downB, blockIdx.x & (NSHARD - 1));
}

// TAIL: conv10..conv13 (<=4 slots) + feat assembly + MLP, one 1024-thread block.
__global__ __launch_bounds__(1024) void k_tail(
    const int* __restrict__ cnt, const float* __restrict__ poolsh,
    const char* __restrict__ vals9b, const int* __restrict__ nbr10,
    const int* __restrict__ idx10, const float* __restrict__ wt,
    const float* __restrict__ wm1, const float* __restrict__ bm1,
    const float* __restrict__ wm2, const float* __restrict__ bm2,
    float* __restrict__ out) {
    __shared__ __align__(16) float v10[128];
    __shared__ float v11[32], v12[32], v13[32];
    __shared__ float feat[448], h[256], part[1024];
    __shared__ int s_i10[4], s_n10;
    int t = threadIdx.x;
    int ciq = t & 7, co = (t >> 3) & 31, s = t >> 8;
    int ciq16 = ciq << 4;
    if (t == 0) s_n10 = cnt[10];
    if (t < 4) s_i10[t] = idx10[t];
    __syncthreads();
    int n10 = s_n10; if (n10 > 4) n10 = 4;
    // conv10: 4 slot-groups x 256 threads, byte-offset gather (zero-row padded)
    {
        const float* wl = wt + (size_t)9 * 9216;
        float4 wreg[9];
        #pragma unroll
        for (int tap = 0; tap < 9; tap++)
            wreg[tap] = *(const float4*)(wl + ((tap * 32 + co) << 5) + (ciq << 2));
        bool live = s < n10;
        int sb = live ? s : 0;
        float a0 = 0.f;
        #pragma unroll
        for (int tap = 0; tap < 9; tap++)
            a0 = fma4(*(const float4*)(vals9b + nbr10[sb * 9 + tap] + ciq16), wreg[tap], a0);
        a0 += __shfl_xor(a0, 1); a0 += __shfl_xor(a0, 2); a0 += __shfl_xor(a0, 4);
        if (ciq == 0 && live) v10[s * 32 + co] = fmaxf(a0, 0.f);
    }
    __syncthreads();
    // down11 neighbor map (level-10 H=2 -> level-11 H=1)
    int i10[4] = {s_i10[0], s_i10[1], s_i10[2], s_i10[3]};
    int nbr11[9];
    #pragma unroll
    for (int tap = 0; tap < 9; tap++) {
        int a = tap / 3, b = tap - a * 3;
        int rr = a - 1, cc = b - 1;
        nbr11[tap] = ((unsigned)rr < 2u && (unsigned)cc < 2u) ? i10[rr * 2 + cc] : -1;
    }
    int n11 = ((nbr11[4] & nbr11[5] & nbr11[7] & nbr11[8]) >= 0) ? 1 : 0;
    if (s == 0) {   // conv11 from LDS v10
        const float* wl = wt + (size_t)10 * 9216;
        float a0 = 0.f;
        #pragma unroll
        for (int tap = 0; tap < 9; tap++) {
            int j = nbr11[tap];
            if (j >= 0) {
                float4 wv = *(const float4*)(wl + ((tap * 32 + co) << 5) + (ciq << 2));
                a0 = fma4(*(const float4*)(&v10[(j << 5) + (ciq << 2)]), wv, a0);
            }
        }
        a0 += __shfl_xor(a0, 1); a0 += __shfl_xor(a0, 2); a0 += __shfl_xor(a0, 4);
        if (ciq == 0) v11[co] = n11 ? fmaxf(a0, 0.f) : 0.f;
    }
    __syncthreads();
    if (s == 0) {   // conv12: center tap only
        const float* wl = wt + (size_t)11 * 9216;
        float4 wv = *(const float4*)(wl + ((4 * 32 + co) << 5) + (ciq << 2));
        float a0 = n11 ? fma4(*(const float4*)(&v11[ciq << 2]), wv, 0.f) : 0.f;
        a0 += __shfl_xor(a0, 1); a0 += __shfl_xor(a0, 2); a0 += __shfl_xor(a0, 4);
        if (ciq == 0) v12[co] = n11 ? fmaxf(a0, 0.f) : 0.f;
    }
    __syncthreads();
    if (s == 0) {   // conv13
        const float* wl = wt + (size_t)12 * 9216;
        float4 wv = *(const float4*)(wl + ((4 * 32 + co) << 5) + (ciq << 2));
        float a0 = n11 ? fma4(*(const float4*)(&v12[ciq << 2]), wv, 0.f) : 0.f;
        a0 += __shfl_xor(a0, 1); a0 += __shfl_xor(a0, 2); a0 += __shfl_xor(a0, 4);
        if (ciq == 0) v13[co] = n11 ? fmaxf(a0, 0.f) : 0.f;
    }
    __syncthreads();
    // feat assembly: levels 0..9 from pool shards, 10..13 from LDS
    if (t < 320) {
        float sum = 0.f;
        #pragma unroll
        for (int sh = 0; sh < NSHARD; sh++) sum += poolsh[sh * 448 + t];
        float c = (float)cnt[t >> 5]; if (c < 1.f) c = 1.f;
        feat[t] = sum / c;
    }
    if (t < 32) {
        float s10 = 0.f;
        for (int q = 0; q < n10; q++) s10 += v10[q * 32 + t];
        float c10 = (float)n10; if (c10 < 1.f) c10 = 1.f;
        feat[320 + t] = s10 / c10;
        feat[352 + t] = n11 ? v11[t] : 0.f;
        feat[384 + t] = n11 ? v12[t] : 0.f;
        feat[416 + t] = n11 ? v13[t] : 0.f;
    }
    __syncthreads();
    // MLP stage 1: 448 -> 256 (4 k-chunks of 112)
    {
        int j = t & 255, chunk = t >> 8;
        float acc = (chunk == 0) ? bm1[j] : 0.f;
        int k0 = chunk * 112;
        #pragma unroll 8
        for (int k = k0; k < k0 + 112; k++) acc = fmaf(feat[k], wm1[k * 256 + j], acc);
        part[t] = acc;
    }
    __syncthreads();
    if (t < 256)
        h[t] = fmaxf(part[t] + part[t + 256] + part[t + 512] + part[t + 768], 0.f);
    __syncthreads();
    // MLP stage 2: 256 -> 128 (8 k-chunks of 32)
    {
        int j2 = t & 127, c2 = t >> 7;
        float a2 = (c2 == 0) ? bm2[j2] : 0.f;
        int kk0 = c2 * 32;
        #pragma unroll 8
        for (int k = kk0; k < kk0 + 32; k++) a2 = fmaf(h[k], wm2[k * 128 + j2], a2);
        part[t] = a2;
    }
    __syncthreads();
    if (t < 128) {
        float sum = 0.f;
        #pragma unroll
        for (int c = 0; c < 8; c++) sum += part[t + 128 * c];
        out[t] = sum;
    }
}

extern "C" void kernel_launch(void* const* d_in, const int* in_sizes, int n_in,
                              void* d_out, int out_size, void* d_ws, size_t ws_size,
                              hipStream_t stream) {
    const float* x    = (const float*)d_in[0];
    const float* mask = (const float*)d_in[1];
    const float* w1   = (const float*)d_in[2];
    const float* wsrc = (const float*)d_in[3];
    const float* wm1  = (const float*)d_in[4];
    const float* bm1  = (const float*)d_in[5];
    const float* wm2  = (const float*)d_in[6];
    const float* bm2  = (const float*)d_in[7];
    float* out = (float*)d_out;
    char* ws = (char*)d_ws;

    static const int Hb[NLVL]   = {11, 10, 9, 8, 7, 6, 5, 4, 3, 2, 1, 0, 0, 0};
    static const int caps[NLVL] = {45056, 43008, 43008, 34816, 16384, 4096,
                                   1024, 256, 64, 16, 4, 1, 1, 1};

    // ws layout: cnt[16]@0, dummy@128, pool shards@256 (16*448 f32), wt@32768
    size_t pool_off = 256;
    size_t wt_off = 32768;
    size_t off = wt_off + (size_t)13 * 9 * 1024 * 4;
    off = (off + 255) & ~(size_t)255;
    size_t coord0_off = off; off += (size_t)caps[0] * 4; off = (off + 255) & ~(size_t)255;
    size_t idx_off[NLVL], nbr_off[NLVL], val_off[NLVL];
    for (int l = 0; l < NLVL; l++) {
        size_t S = (size_t)(1 << Hb[l]) * (1 << Hb[l]);
        size_t sb = S * 4; if (sb < 16) sb = 16;
        idx_off[l] = off; off += sb; off = (off + 255) & ~(size_t)255;
        if (l >= 1) { nbr_off[l] = off; off += (size_t)caps[l] * 36; off = (off + 255) & ~(size_t)255; }
        else nbr_off[l] = 0;
        val_off[l] = off; off += (size_t)(caps[l] + 1) * 128; off = (off + 255) & ~(size_t)255;
    }

    int* cnt = (int*)ws;
    float* poolsh = (float*)(ws + pool_off);
    float* dummy = (float*)(ws + 128);
    float* wt = (float*)(ws + wt_off);

    ZeroArgs za;
    for (int l = 0; l < 13; l++) za.zoff[l] = val_off[l] + (size_t)caps[l] * 128;

    hipMemsetAsync(ws, 0, 32768, stream);   // cnt + pool shards

    k_f0<<<1493, 256, 0, stream>>>(
        (const float4*)mask, (int*)(ws + idx_off[0]), (int*)(ws + coord0_off),
        cnt, caps[0], wsrc, wt, ws, za);

    k_f1<<<3096, 256, 0, stream>>>(
        (const int*)(ws + idx_off[0]), (int*)(ws + idx_off[1]), (int*)(ws + nbr_off[1]),
        cnt + 1, caps[1], caps[0] * 128,
        x, w1, (const int*)(ws + coord0_off), cnt, caps[0],
        (float*)(ws + val_off[0]), poolsh, wm1, wm2, dummy);

    for (int i = 2; i <= 10; i++) {
        int lc = i - 1;
        int Hout = 1 << Hb[i];
        int S4 = (Hout * Hout + 3) >> 2;
        int downB = (S4 + 255) >> 8; if (downB < 1) downB = 1;
        int convB = (caps[lc] + 15) >> 4;
        k_flevel<<<downB + convB, 256, 0, stream>>>(
            downB,
            (const int*)(ws + idx_off[i - 1]), Hb[i - 1],
            (int*)(ws + idx_off[i]), (int*)(ws + nbr_off[i]), cnt + i, Hb[i], caps[i],
            caps[i - 1] * 128,
            (const char*)(ws + val_off[lc - 1]), wt + (size_t)(lc - 1) * 9216,
            (const int*)(ws + nbr_off[lc]), cnt + lc, caps[lc],
            (float*)(ws + val_off[lc]), poolsh + lc * 32);
    }

    k_tail<<<1, 1024, 0, stream>>>(
        cnt, poolsh,
        (const char*)(ws + val_off[9]), (const int*)(ws + nbr_off[10]),
        (const int*)(ws + idx_off[10]), wt,
        wm1, bm1, wm2, bm2, out);
}

// Round 8
// 267.119 us; speedup vs baseline: 1.5477x; 1.3150x over previous
//
#include <hip/hip_runtime.h>

#define NLVL 14
#define NSHARD 16

struct ZeroArgs { unsigned long long zoff[13]; };

__device__ __forceinline__ float fma4(float4 v, float4 w, float acc) {
    acc = fmaf(v.x, w.x, acc);
    acc = fmaf(v.y, w.y, acc);
    acc = fmaf(v.z, w.z, acc);
    return fmaf(v.w, w.w, acc);
}

// exclusive prefix over a 256-thread block, one atomicAdd per block.
__device__ __forceinline__ int block_scan_base(int mycnt, int* gcnt, int& myoff) {
    __shared__ int wsum[4];
    __shared__ int base;
    int lane = threadIdx.x & 63, wid = threadIdx.x >> 6;
    int scan = mycnt;
    #pragma unroll
    for (int d = 1; d < 64; d <<= 1) {
        int tv = __shfl_up(scan, d, 64);
        if (lane >= d) scan += tv;
    }
    if (lane == 63) wsum[wid] = scan;
    __syncthreads();
    if (threadIdx.x == 0) {
        int tot = 0;
        #pragma unroll
        for (int i = 0; i < 4; i++) { int tv = wsum[i]; wsum[i] = tot; tot += tv; }
        base = tot ? atomicAdd(gcnt, tot) : 0;
    }
    __syncthreads();
    myoff = wsum[wid] + scan - mycnt;
    return base;
}

// ---- level-0 mask compaction tile ----
__device__ void compact0_tile(const float4* __restrict__ mask4, int* __restrict__ idxmap,
                              int* __restrict__ coords, int* __restrict__ cnt, int cap, int tile) {
    int t = threadIdx.x;
    int g0 = tile * 1024 + t;
    float4 m[4];
    #pragma unroll
    for (int j = 0; j < 4; j++) m[j] = mask4[g0 + j * 256];
    int pr[16];
    int mycnt = 0;
    #pragma unroll
    for (int j = 0; j < 4; j++) {
        pr[4 * j + 0] = m[j].x > 0.5f;
        pr[4 * j + 1] = m[j].y > 0.5f;
        pr[4 * j + 2] = m[j].z > 0.5f;
        pr[4 * j + 3] = m[j].w > 0.5f;
        mycnt += pr[4 * j] + pr[4 * j + 1] + pr[4 * j + 2] + pr[4 * j + 3];
    }
    int myoff;
    int base = block_scan_base(mycnt, cnt, myoff);
    int slot = base + myoff;
    #pragma unroll
    for (int j = 0; j < 4; j++) {
        int e0 = (g0 + j * 256) << 2;
        int wv[4];
        #pragma unroll
        for (int k = 0; k < 4; k++) {
            wv[k] = -1;
            if (pr[4 * j + k]) {
                int sl = slot++;
                if (sl < cap) { wv[k] = sl; coords[sl] = e0 + k; }
            }
        }
        *(int4*)(idxmap + e0) = make_int4(wv[0], wv[1], wv[2], wv[3]);
    }
}

// ---- downsample + neighbor lists (byte offsets into vals_{l-1}, zero-row remap) ----
__device__ void down_nbr(const int* __restrict__ idx_in, int HinB,
                         int* __restrict__ idx_out, int* __restrict__ nbr_out,
                         int* __restrict__ cnt_out, int HoutB, int cap_out,
                         int zofs, int bb) {
    int Hout = 1 << HoutB, Hin = 1 << HinB;
    int S = Hout * Hout;
    int S4 = (S + 3) >> 2;
    int o4 = bb * 256 + threadIdx.x;
    int e0 = o4 << 2;
    int jv[4][9];
    int pr[4] = {0, 0, 0, 0};
    #pragma unroll
    for (int k = 0; k < 4; k++)
        #pragma unroll
        for (int tap = 0; tap < 9; tap++) jv[k][tap] = -1;
    if (o4 < S4) {
        if (HoutB >= 2) {
            int r = e0 >> HoutB, c0 = e0 & (Hout - 1);
            int w[3][12];
            #pragma unroll
            for (int a = 0; a < 3; a++) {
                int rr = 2 * r + a - 1;
                bool rok = (unsigned)rr < (unsigned)Hin;
                const int* rowp = idx_in + ((size_t)(rok ? rr : 0) << HinB) + 2 * c0;
                int4 L = (rok && c0 > 0) ? *(const int4*)(rowp - 4) : make_int4(-1, -1, -1, -1);
                int4 M = rok ? *(const int4*)rowp : make_int4(-1, -1, -1, -1);
                int4 R = rok ? *(const int4*)(rowp + 4) : make_int4(-1, -1, -1, -1);
                w[a][0] = L.x; w[a][1] = L.y; w[a][2]  = L.z; w[a][3]  = L.w;
                w[a][4] = M.x; w[a][5] = M.y; w[a][6]  = M.z; w[a][7]  = M.w;
                w[a][8] = R.x; w[a][9] = R.y; w[a][10] = R.z; w[a][11] = R.w;
            }
            #pragma unroll
            for (int k = 0; k < 4; k++) {
                #pragma unroll
                for (int a = 0; a < 3; a++)
                    #pragma unroll
                    for (int b = 0; b < 3; b++)
                        jv[k][a * 3 + b] = w[a][2 * k + b + 3];
                pr[k] = ((jv[k][4] & jv[k][5] & jv[k][7] & jv[k][8]) >= 0);
            }
        } else {   // Hout 1 or 2 (scalar path)
            #pragma unroll
            for (int k = 0; k < 4; k++) {
                int p = e0 + k;
                if (p < S) {
                    int r = p >> HoutB, c = p & (Hout - 1);
                    #pragma unroll
                    for (int a = 0; a < 3; a++)
                        #pragma unroll
                        for (int b = 0; b < 3; b++) {
                            int rr = 2 * r + a - 1, cc = 2 * c + b - 1;
                            if ((unsigned)rr < (unsigned)Hin && (unsigned)cc < (unsigned)Hin)
                                jv[k][a * 3 + b] = idx_in[((size_t)rr << HinB) + cc];
                        }
                    pr[k] = ((jv[k][4] & jv[k][5] & jv[k][7] & jv[k][8]) >= 0);
                }
            }
        }
    }
    int mycnt = pr[0] + pr[1] + pr[2] + pr[3];
    int myoff;
    int base = block_scan_base(mycnt, cnt_out, myoff);
    int slot = base + myoff;
    int wv[4] = {-1, -1, -1, -1};
    #pragma unroll
    for (int k = 0; k < 4; k++) {
        if (pr[k]) {
            int sl = slot++;
            if (sl < cap_out) {
                wv[k] = sl;
                #pragma unroll
                for (int tap = 0; tap < 9; tap++) {
                    int j = jv[k][tap];
                    nbr_out[sl * 9 + tap] = (j < 0) ? zofs : (j << 7);
                }
            }
        }
    }
    if (o4 < S4) {
        if (S >= 4) *(int4*)(idx_out + e0) = make_int4(wv[0], wv[1], wv[2], wv[3]);
        else {
            #pragma unroll
            for (int k = 0; k < 4; k++) if (e0 + k < S) idx_out[e0 + k] = wv[k];
        }
    }
}

// ---- conv 3x3 s2 32->32: LDS-staged inputs (1x fetch), co-pair compute ----
// thread = (ciq = t&7, coh = (t>>3)&15 -> co {coh, coh+16}, sp = t>>7)
__device__ void conv_bs(const char* __restrict__ vprevb, const float* __restrict__ wlvl,
                        const int* __restrict__ nbr, int n,
                        float* __restrict__ vals, float* __restrict__ poolp,
                        int b0, int nbk, int shard) {
    __shared__ int s_j[144];
    __shared__ __align__(16) float s_in[144 * 32];   // 18 KB: 16 slots x 9 taps x 32 cin
    int t = threadIdx.x;
    int ciq = t & 7, coh = (t >> 3) & 15, sp = t >> 7;
    float4 wreg[9][2];
    #pragma unroll
    for (int tap = 0; tap < 9; tap++) {
        wreg[tap][0] = *(const float4*)(wlvl + ((tap * 32 + coh) << 5) + (ciq << 2));
        wreg[tap][1] = *(const float4*)(wlvl + ((tap * 32 + coh + 16) << 5) + (ciq << 2));
    }
    float ps0 = 0.f, ps1 = 0.f;
    int ngr = (n + 15) >> 4;
    for (int grp = b0; grp < ngr; grp += nbk) {
        __syncthreads();
        if (t < 144) {
            int gi = grp * 144 + t;
            s_j[t] = (gi < n * 9) ? nbr[gi] : 0;
        }
        __syncthreads();
        // stage 16 slots x 9 rows x 128 B: 8 lanes per row, 1 KB/wave-instr
        #pragma unroll
        for (int i = t; i < 1152; i += 256) {
            int row = i >> 3, q = i & 7;
            *(float4*)&s_in[(row << 5) + (q << 2)] =
                *(const float4*)(vprevb + s_j[row] + (q << 4));
        }
        __syncthreads();
        #pragma unroll
        for (int gp = 0; gp < 8; gp++) {
            int g = gp * 2 + sp;
            int s = (grp << 4) + g;
            float4 v[9];
            #pragma unroll
            for (int tap = 0; tap < 9; tap++)
                v[tap] = *(const float4*)&s_in[((g * 9 + tap) << 5) + (ciq << 2)];
            float a0 = 0.f, a1 = 0.f;
            #pragma unroll
            for (int tap = 0; tap < 9; tap++) {
                a0 = fma4(v[tap], wreg[tap][0], a0);
                a1 = fma4(v[tap], wreg[tap][1], a1);
            }
            a0 += __shfl_xor(a0, 1); a0 += __shfl_xor(a0, 2); a0 += __shfl_xor(a0, 4);
            a1 += __shfl_xor(a1, 1); a1 += __shfl_xor(a1, 2); a1 += __shfl_xor(a1, 4);
            if (ciq == 0 && s < n) {
                float r0 = fmaxf(a0, 0.f), r1 = fmaxf(a1, 0.f);
                vals[((size_t)s << 5) + coh] = r0;
                vals[((size_t)s << 5) + coh + 16] = r1;
                ps0 += r0; ps1 += r1;
            }
        }
    }
    if (ciq == 0 && (ps0 != 0.f || ps1 != 0.f)) {
        atomicAdd(&poolp[shard * 448 + coh], ps0);
        atomicAdd(&poolp[shard * 448 + coh + 16], ps1);
    }
}

// ---- conv0 (5x5, cin=1): LDS-staged windows, folded pool ----
__device__ void conv0_bs(const float* __restrict__ x, const float* __restrict__ w1,
                         const int* __restrict__ coords0, int n,
                         float* __restrict__ vals0, float* __restrict__ poolp,
                         int b0, int nbk, int shard) {
    __shared__ float lw[800];
    __shared__ float lx[8][28];
    __shared__ float red[256];
    int t = threadIdx.x;
    for (int i = t; i < 800; i += 256) lw[i] = w1[i];
    int sl = t >> 5, ch = t & 31;
    float psum = 0.f;
    int ngr = (n + 7) >> 3;
    for (int grp = b0; grp < ngr; grp += nbk) {
        __syncthreads();
        if (t < 200) {
            int slot = t / 25, tap = t - slot * 25;
            int s = (grp << 3) + slot;
            float v = 0.f;
            if (s < n) {
                int p = coords0[s];
                int r = p >> 11, c = p & 2047;
                int a = tap / 5, b = tap - a * 5;
                int rr = r + a - 2, cc = c + b - 2;
                if ((unsigned)rr < 2048u && (unsigned)cc < 2048u)
                    v = x[(rr << 11) + cc];
            }
            lx[slot][tap] = v;
        }
        __syncthreads();
        int s = (grp << 3) + sl;
        float acc = 0.f;
        #pragma unroll
        for (int tap = 0; tap < 25; tap++)
            acc = fmaf(lx[sl][tap], lw[tap * 32 + ch], acc);
        if (s < n) {
            float r0 = fmaxf(acc, 0.f);
            vals0[((size_t)s << 5) + ch] = r0;
            psum += r0;
        }
    }
    __syncthreads();
    red[t] = psum;
    __syncthreads();
    if (t < 32) {
        float tot = 0.f;
        #pragma unroll
        for (int q = 0; q < 8; q++) tot += red[t + 32 * q];
        if (tot != 0.f) atomicAdd(&poolp[shard * 448 + t], tot);
    }
}

// F0 = compaction (0..1023) + weight transpose (1024..1491) + zero-rows (1492)
__global__ __launch_bounds__(256) void k_f0(
    const float4* __restrict__ mask4, int* __restrict__ idxmap,
    int* __restrict__ coords, int* __restrict__ cnt, int cap,
    const float* __restrict__ w, float* __restrict__ wt,
    char* __restrict__ wsbase, ZeroArgs za) {
    if (blockIdx.x == 1492) {
        for (int i = threadIdx.x; i < 13 * 32; i += 256)
            *(float*)(wsbase + za.zoff[i >> 5] + ((i & 31) << 2)) = 0.f;
        return;
    }
    if (blockIdx.x >= 1024) {
        int t = (int)(blockIdx.x - 1024) * 256 + threadIdx.x;
        if (t < 13 * 9 * 32 * 32) {
            int ci = t & 31, co = (t >> 5) & 31, tp = t >> 10;
            wt[(tp << 10) + (co << 5) + ci] = w[(tp << 10) + (ci << 5) + co];
        }
        return;
    }
    compact0_tile(mask4, idxmap, coords, cnt, cap, blockIdx.x);
}

// F1 = down1+nbr1 (0..1023) + conv0 (1024..5119) + wm warm (5120..5143)
__global__ __launch_bounds__(256) void k_f1(
    const int* __restrict__ idx0, int* __restrict__ idx1, int* __restrict__ nbr1,
    int* __restrict__ cnt1, int cap1, int zofs1,
    const float* __restrict__ x, const float* __restrict__ w1,
    const int* __restrict__ coords0, const int* __restrict__ cnt0, int cap0,
    float* __restrict__ vals0, float* __restrict__ poolp,
    const float* __restrict__ wm1, const float* __restrict__ wm2, float* __restrict__ dummy) {
    if (blockIdx.x < 1024) {
        down_nbr(idx0, 11, idx1, nbr1, cnt1, 10, cap1, zofs1, blockIdx.x);
        return;
    }
    if (blockIdx.x >= 5120) {
        int t = (int)(blockIdx.x - 5120) * 256 + threadIdx.x;
        const float4* a = (const float4*)wm1;
        const float4* b = (const float4*)wm2;
        float acc = 0.f;
        for (int i = t; i < 28672; i += 6144) { float4 v = a[i]; acc += v.x + v.y + v.z + v.w; }
        for (int i = t; i < 8192; i += 6144)  { float4 v = b[i]; acc += v.x + v.y + v.z + v.w; }
        if (acc == 1234.56789f) dummy[0] = acc;
        return;
    }
    int n = *cnt0; if (n > cap0) n = cap0;
    conv0_bs(x, w1, coords0, n, vals0, poolp, blockIdx.x - 1024, 4096, blockIdx.x & (NSHARD - 1));
}

// F_i (i=2..10): down_i (+nbr_i) fused with conv_{i-1} (+pool_{i-1})
__global__ __launch_bounds__(256) void k_flevel(
    int downB,
    const int* __restrict__ idx_in, int HinB,
    int* __restrict__ idx_out, int* __restrict__ nbr_out, int* __restrict__ cnt_out,
    int HoutB, int cap_out, int zofs,
    const char* __restrict__ vprevb, const float* __restrict__ wlvl,
    const int* __restrict__ nbr_c, const int* __restrict__ cnt_c, int cap_c,
    float* __restrict__ vals_c, float* __restrict__ poolp) {
    if ((int)blockIdx.x < downB) {
        down_nbr(idx_in, HinB, idx_out, nbr_out, cnt_out, HoutB, cap_out, zofs, blockIdx.x);
        return;
    }
    int n = *cnt_c; if (n > cap_c) n = cap_c;
    conv_bs(vprevb, wlvl, nbr_c, n, vals_c, poolp,
            blockIdx.x - downB, gridDim.x - downB, blockIdx.x & (NSHARD - 1));
}

// TAIL: conv10..conv13 (<=4 slots) + feat assembly + MLP, one 1024-thread block.
__global__ __launch_bounds__(1024) void k_tail(
    const int* __restrict__ cnt, const float* __restrict__ poolsh,
    const char* __restrict__ vals9b, const int* __restrict__ nbr10,
    const int* __restrict__ idx10, const float* __restrict__ wt,
    const float* __restrict__ wm1, const float* __restrict__ bm1,
    const float* __restrict__ wm2, const float* __restrict__ bm2,
    float* __restrict__ out) {
    __shared__ __align__(16) float v10[128];
    __shared__ float v11[32], v12[32], v13[32];
    __shared__ float feat[448], h[256], part[1024];
    __shared__ int s_i10[4], s_n10;
    int t = threadIdx.x;
    int ciq = t & 7, co = (t >> 3) & 31, s = t >> 8;
    int ciq16 = ciq << 4;
    if (t == 0) s_n10 = cnt[10];
    if (t < 4) s_i10[t] = idx10[t];
    __syncthreads();
    int n10 = s_n10; if (n10 > 4) n10 = 4;
    // conv10: 4 slot-groups x 256 threads, byte-offset gather (zero-row padded)
    {
        const float* wl = wt + (size_t)9 * 9216;
        float4 wreg[9];
        #pragma unroll
        for (int tap = 0; tap < 9; tap++)
            wreg[tap] = *(const float4*)(wl + ((tap * 32 + co) << 5) + (ciq << 2));
        bool live = s < n10;
        int sb = live ? s : 0;
        float a0 = 0.f;
        #pragma unroll
        for (int tap = 0; tap < 9; tap++)
            a0 = fma4(*(const float4*)(vals9b + nbr10[sb * 9 + tap] + ciq16), wreg[tap], a0);
        a0 += __shfl_xor(a0, 1); a0 += __shfl_xor(a0, 2); a0 += __shfl_xor(a0, 4);
        if (ciq == 0 && live) v10[s * 32 + co] = fmaxf(a0, 0.f);
    }
    __syncthreads();
    // down11 neighbor map (level-10 H=2 -> level-11 H=1)
    int i10[4] = {s_i10[0], s_i10[1], s_i10[2], s_i10[3]};
    int nbr11[9];
    #pragma unroll
    for (int tap = 0; tap < 9; tap++) {
        int a = tap / 3, b = tap - a * 3;
        int rr = a - 1, cc = b - 1;
        nbr11[tap] = ((unsigned)rr < 2u && (unsigned)cc < 2u) ? i10[rr * 2 + cc] : -1;
    }
    int n11 = ((nbr11[4] & nbr11[5] & nbr11[7] & nbr11[8]) >= 0) ? 1 : 0;
    if (s == 0) {   // conv11 from LDS v10
        const float* wl = wt + (size_t)10 * 9216;
        float a0 = 0.f;
        #pragma unroll
        for (int tap = 0; tap < 9; tap++) {
            int j = nbr11[tap];
            if (j >= 0) {
                float4 wv = *(const float4*)(wl + ((tap * 32 + co) << 5) + (ciq << 2));
                a0 = fma4(*(const float4*)(&v10[(j << 5) + (ciq << 2)]), wv, a0);
            }
        }
        a0 += __shfl_xor(a0, 1); a0 += __shfl_xor(a0, 2); a0 += __shfl_xor(a0, 4);
        if (ciq == 0) v11[co] = n11 ? fmaxf(a0, 0.f) : 0.f;
    }
    __syncthreads();
    if (s == 0) {   // conv12: center tap only
        const float* wl = wt + (size_t)11 * 9216;
        float4 wv = *(const float4*)(wl + ((4 * 32 + co) << 5) + (ciq << 2));
        float a0 = n11 ? fma4(*(const float4*)(&v11[ciq << 2]), wv, 0.f) : 0.f;
        a0 += __shfl_xor(a0, 1); a0 += __shfl_xor(a0, 2); a0 += __shfl_xor(a0, 4);
        if (ciq == 0) v12[co] = n11 ? fmaxf(a0, 0.f) : 0.f;
    }
    __syncthreads();
    if (s == 0) {   // conv13
        const float* wl = wt + (size_t)12 * 9216;
        float4 wv = *(const float4*)(wl + ((4 * 32 + co) << 5) + (ciq << 2));
        float a0 = n11 ? fma4(*(const float4*)(&v12[ciq << 2]), wv, 0.f) : 0.f;
        a0 += __shfl_xor(a0, 1); a0 += __shfl_xor(a0, 2); a0 += __shfl_xor(a0, 4);
        if (ciq == 0) v13[co] = n11 ? fmaxf(a0, 0.f) : 0.f;
    }
    __syncthreads();
    // feat assembly: levels 0..9 from pool shards, 10..13 from LDS
    if (t < 320) {
        float sum = 0.f;
        #pragma unroll
        for (int sh = 0; sh < NSHARD; sh++) sum += poolsh[sh * 448 + t];
        float c = (float)cnt[t >> 5]; if (c < 1.f) c = 1.f;
        feat[t] = sum / c;
    }
    if (t < 32) {
        float s10 = 0.f;
        for (int q = 0; q < n10; q++) s10 += v10[q * 32 + t];
        float c10 = (float)n10; if (c10 < 1.f) c10 = 1.f;
        feat[320 + t] = s10 / c10;
        feat[352 + t] = n11 ? v11[t] : 0.f;
        feat[384 + t] = n11 ? v12[t] : 0.f;
        feat[416 + t] = n11 ? v13[t] : 0.f;
    }
    __syncthreads();
    // MLP stage 1: 448 -> 256 (4 k-chunks of 112)
    {
        int j = t & 255, chunk = t >> 8;
        float acc = (chunk == 0) ? bm1[j] : 0.f;
        int k0 = chunk * 112;
        #pragma unroll 8
        for (int k = k0; k < k0 + 112; k++) acc = fmaf(feat[k], wm1[k * 256 + j], acc);
        part[t] = acc;
    }
    __syncthreads();
    if (t < 256)
        h[t] = fmaxf(part[t] + part[t + 256] + part[t + 512] + part[t + 768], 0.f);
    __syncthreads();
    // MLP stage 2: 256 -> 128 (8 k-chunks of 32)
    {
        int j2 = t & 127, c2 = t >> 7;
        float a2 = (c2 == 0) ? bm2[j2] : 0.f;
        int kk0 = c2 * 32;
        #pragma unroll 8
        for (int k = kk0; k < kk0 + 32; k++) a2 = fmaf(h[k], wm2[k * 128 + j2], a2);
        part[t] = a2;
    }
    __syncthreads();
    if (t < 128) {
        float sum = 0.f;
        #pragma unroll
        for (int c = 0; c < 8; c++) sum += part[t + 128 * c];
        out[t] = sum;
    }
}

extern "C" void kernel_launch(void* const* d_in, const int* in_sizes, int n_in,
                              void* d_out, int out_size, void* d_ws, size_t ws_size,
                              hipStream_t stream) {
    const float* x    = (const float*)d_in[0];
    const float* mask = (const float*)d_in[1];
    const float* w1   = (const float*)d_in[2];
    const float* wsrc = (const float*)d_in[3];
    const float* wm1  = (const float*)d_in[4];
    const float* bm1  = (const float*)d_in[5];
    const float* wm2  = (const float*)d_in[6];
    const float* bm2  = (const float*)d_in[7];
    float* out = (float*)d_out;
    char* ws = (char*)d_ws;

    static const int Hb[NLVL]   = {11, 10, 9, 8, 7, 6, 5, 4, 3, 2, 1, 0, 0, 0};
    static const int caps[NLVL] = {45056, 43008, 43008, 34816, 16384, 4096,
                                   1024, 256, 64, 16, 4, 1, 1, 1};

    // ws layout: cnt[16]@0, dummy@128, pool shards@256 (16*448 f32), wt@32768
    size_t pool_off = 256;
    size_t wt_off = 32768;
    size_t off = wt_off + (size_t)13 * 9 * 1024 * 4;
    off = (off + 255) & ~(size_t)255;
    size_t coord0_off = off; off += (size_t)caps[0] * 4; off = (off + 255) & ~(size_t)255;
    size_t idx_off[NLVL], nbr_off[NLVL], val_off[NLVL];
    for (int l = 0; l < NLVL; l++) {
        size_t S = (size_t)(1 << Hb[l]) * (1 << Hb[l]);
        size_t sb = S * 4; if (sb < 16) sb = 16;
        idx_off[l] = off; off += sb; off = (off + 255) & ~(size_t)255;
        if (l >= 1) { nbr_off[l] = off; off += (size_t)caps[l] * 36; off = (off + 255) & ~(size_t)255; }
        else nbr_off[l] = 0;
        val_off[l] = off; off += (size_t)(caps[l] + 1) * 128; off = (off + 255) & ~(size_t)255;
    }

    int* cnt = (int*)ws;
    float* poolsh = (float*)(ws + pool_off);
    float* dummy = (float*)(ws + 128);
    float* wt = (float*)(ws + wt_off);

    ZeroArgs za;
    for (int l = 0; l < 13; l++) za.zoff[l] = val_off[l] + (size_t)caps[l] * 128;

    hipMemsetAsync(ws, 0, 32768, stream);   // cnt + pool shards

    k_f0<<<1493, 256, 0, stream>>>(
        (const float4*)mask, (int*)(ws + idx_off[0]), (int*)(ws + coord0_off),
        cnt, caps[0], wsrc, wt, ws, za);

    k_f1<<<5144, 256, 0, stream>>>(
        (const int*)(ws + idx_off[0]), (int*)(ws + idx_off[1]), (int*)(ws + nbr_off[1]),
        cnt + 1, caps[1], caps[0] * 128,
        x, w1, (const int*)(ws + coord0_off), cnt, caps[0],
        (float*)(ws + val_off[0]), poolsh, wm1, wm2, dummy);

    for (int i = 2; i <= 10; i++) {
        int lc = i - 1;
        int Hout = 1 << Hb[i];
        int S4 = (Hout * Hout + 3) >> 2;
        int downB = (S4 + 255) >> 8; if (downB < 1) downB = 1;
        int convB = (caps[lc] + 15) >> 4;
        k_flevel<<<downB + convB, 256, 0, stream>>>(
            downB,
            (const int*)(ws + idx_off[i - 1]), Hb[i - 1],
            (int*)(ws + idx_off[i]), (int*)(ws + nbr_off[i]), cnt + i, Hb[i], caps[i],
            caps[i - 1] * 128,
            (const char*)(ws + val_off[lc - 1]), wt + (size_t)(lc - 1) * 9216,
            (const int*)(ws + nbr_off[lc]), cnt + lc, caps[lc],
            (float*)(ws + val_off[lc]), poolsh + lc * 32);
    }

    k_tail<<<1, 1024, 0, stream>>>(
        cnt, poolsh,
        (const char*)(ws + val_off[9]), (const int*)(ws + nbr_off[10]),
        (const int*)(ws + idx_off[10]), wt,
        wm1, bm1, wm2, bm2, out);
}